// Round 14
// baseline (78.557 us; speedup 1.0000x reference)
//
#include <hip/hip_runtime.h>
#include <hip/hip_fp16.h>

#define OUT_H 7
#define OUT_W 7
#define NPOS  49
#define RATIO 2
#define SCALE 0.25f
#define CCH 256
#define FH 200
#define FW 200
#define FHW (FH * FW)          // 40000
#define PIXB (CCH * 2)         // 512 B per pixel row in featT
#define DEPTH 3                // staging ring slots per wave

// ---------------- Transpose: (B, 256, 40000) fp32 -> (B, 40000, 256) fp16 ---
// Proven ~15 us (HBM-bound: 123 MB moved). Do not touch.
__global__ __launch_bounds__(256) void transpose_cp(
    const float* __restrict__ in, __half* __restrict__ outT)
{
    int bid = blockIdx.x;               // grid = B * 4 * 625
    int pt   = bid % 625;               // pixel tile (64 pixels)
    int rest = bid / 625;
    int ct   = rest & 3;                // channel tile (64 ch)
    int b    = rest >> 2;

    __shared__ unsigned short tile[64][66];   // [pix][c]
    int tid = threadIdx.x;
    int pix0 = pt * 64, c0 = ct * 64;
    int xl = tid & 63;

    const float* src = in + ((size_t)b * CCH + c0) * FHW + pix0;
    #pragma unroll
    for (int k = 0; k < 16; ++k) {
        int cl = (tid >> 6) + 4 * k;    // 0..63
        tile[xl][cl] = __half_as_ushort(__float2half(src[(size_t)cl * FHW + xl]));
    }
    __syncthreads();

    __half* dst = outT + ((size_t)b * FHW + pix0) * CCH + c0;
    #pragma unroll
    for (int j = 0; j < 8; ++j) {
        int idx = tid + 256 * j;        // 0..2047
        int pl = idx >> 5;              // 0..63
        int cp = idx & 31;              // half2 index: c = 2*cp
        *(unsigned int*)((char*)dst + (size_t)pl * (CCH * 2) + 4 * cp) =
            *(const unsigned int*)&tile[pl][2 * cp];
    }
}

// Async 16B/lane global->LDS. LDS dest = uniform base + lane*16 (HW rule);
// global source address is PER-LANE (may be scattered).
__device__ __forceinline__ void gload16(const void* g, void* s) {
    __builtin_amdgcn_global_load_lds(
        (const __attribute__((address_space(1))) void*)g,
        (__attribute__((address_space(3))) void*)s, 16, 0, 0);
}

// ---------------- ROI Align gather v12: table-driven async pipeline ---------
// v11's pipeline (async global_load_lds staging, counted vmcnt) was correct
// but VALU-bound (83%): every lane recomputed coords/weights (~92 VALU/pos).
// v12 hoists ALL per-ROI math into LDS tables computed ONCE per block:
//   atab[p][s][c] = corner byte offset (u32), wtab[p][s][c] = folded weight.
// Stage   = 2 table ds_reads + 2 async gloads (no float math).
// Consume = 16 x (ds_read_u16 + v_fma_mix) with broadcast weight reads.
__global__ __launch_bounds__(256, 3) void roi_gather_v12(
    const __half* __restrict__ featT,  // (B, 40000, 256) fp16
    const float* __restrict__ rois,    // (N, 5)
    float* __restrict__ out,           // (N, 256, 7, 7)
    int N)
{
    int bid = blockIdx.x;
    int n  = bid >> 2;
    int cq = bid & 3;
    int tid  = threadIdx.x;
    int wv   = tid >> 6;                // wave 0..3
    int lane = tid & 63;

    __shared__ __half   pix[4][DEPTH][1024];   // 24 KB staging ring
    __shared__ float    ldso[NPOS * 65];       // 12.7 KB output staging
    __shared__ uint32_t atab[NPOS * 16];       // 3.1 KB corner offsets
    __shared__ float    wtab[NPOS * 16];       // 3.1 KB corner weights

    const float* r = rois + (size_t)n * 5;
    int   b  = (int)r[0];
    float x1 = r[1] * SCALE, y1 = r[2] * SCALE;
    float roi_w = fmaxf(r[3] * SCALE - x1, 1.0f);
    float roi_h = fmaxf(r[4] * SCALE - y1, 1.0f);
    float step_x = roi_w * (1.0f / (OUT_W * RATIO));
    float step_y = roi_h * (1.0f / (OUT_H * RATIO));

    // ---- per-block precompute: 784 (pos, sample, corner) entries ----
    #pragma unroll 1
    for (int t = tid; t < NPOS * 16; t += 256) {
        int p = t >> 4;
        int s = (t >> 2) & 3;
        int c = t & 3;
        int ph = p / OUT_W, pw = p - (p / OUT_W) * OUT_W;
        int iy = s >> 1, ix = s & 1;
        float yy = y1 + ((float)(ph * RATIO + iy) + 0.5f) * step_y;
        float xx = x1 + ((float)(pw * RATIO + ix) + 0.5f) * step_x;
        bool  vv = (yy >= -1.0f) && (yy <= (float)FH)
                && (xx >= -1.0f) && (xx <= (float)FW);
        float yc = fminf(fmaxf(yy, 0.0f), (float)(FH - 1));
        float xc = fminf(fmaxf(xx, 0.0f), (float)(FW - 1));
        int yi0 = (int)yc, xi0 = (int)xc;
        float ly = yc - (float)yi0, hy = 1.0f - ly;
        float lx = xc - (float)xi0, hx = 1.0f - lx;
        uint32_t rw = (uint32_t)(yi0 * FW + xi0) * PIXB;
        uint32_t dx = (xi0 < FW - 1) ? PIXB : 0u;
        uint32_t dy = (yi0 < FH - 1) ? (FW * PIXB) : 0u;
        atab[t] = rw + ((c & 1) ? dx : 0u) + ((c & 2) ? dy : 0u);
        float vm = vv ? 0.25f : 0.0f;
        wtab[t] = ((c & 2) ? ly : hy) * ((c & 1) ? lx : hx) * vm;
    }
    __syncthreads();

    const char* base = (const char*)featT + (size_t)b * ((size_t)FHW * PIXB)
                     + (uint32_t)cq * 128;
    const int qa = lane >> 3;                        // quarter 0..7 per gload
    const uint32_t bq = (uint32_t)(lane & 7) * 16;   // byte within 128B quarter

    const int nk = ((48 - wv) >> 2) + 1;    // 13,12,12,12

    auto stage = [&](int k) {
        int p = wv + 4 * k;
        uint32_t a0 = atab[p * 16 + qa];        // samples 0/1
        uint32_t a1 = atab[p * 16 + 8 + qa];    // samples 2/3
        __half* dst = &pix[wv][k % DEPTH][0];
        gload16(base + a0 + bq, (void*)dst);
        gload16(base + a1 + bq, (void*)(dst + 512));  // +1024 B
    };

    auto consume = [&](int k) {
        int p = wv + 4 * k;
        const __half* src = &pix[wv][k % DEPTH][0];
        const float* wp = &wtab[p * 16];
        float acc = 0.0f;
        #pragma unroll
        for (int q = 0; q < 16; ++q)
            acc = fmaf(__half2float(src[q * 64 + lane]), wp[q], acc);
        ldso[p * 65 + lane] = acc;    // banks (p+lane)%32: 2/bank = free
    };

    // ---- software pipeline: 2 positions ahead, counted vmcnt ----
    stage(0);
    stage(1);
    #pragma unroll 1
    for (int k = 0; k < nk; ++k) {
        if (k + 2 < nk) {
            stage(k + 2);
            asm volatile("s_waitcnt vmcnt(4)" ::: "memory");  // k's 2 loads done
        } else if (k + 1 < nk) {
            asm volatile("s_waitcnt vmcnt(2)" ::: "memory");
        } else {
            asm volatile("s_waitcnt vmcnt(0)" ::: "memory");
        }
        consume(k);
    }
    __syncthreads();

    // Contiguous 64*49-float region of (N,C,7,7); write-once -> nontemporal.
    float* oblk = out + ((size_t)n * CCH + cq * 64) * NPOS;
    #pragma unroll 1
    for (int o = tid; o < 64 * NPOS; o += 256) {
        int c = o / NPOS;          // magic-mul
        int p = o - c * NPOS;
        __builtin_nontemporal_store(ldso[p * 65 + c], &oblk[o]);
    }
}

// ---------------- Fallback: direct NCHW (round-1 kernel) --------------------
__global__ __launch_bounds__(256) void roi_align_kernel(
    const float* __restrict__ feat, const float* __restrict__ rois,
    float* __restrict__ out, int N, int C, int H, int W)
{
    int idx = blockIdx.x * blockDim.x + threadIdx.x;
    int total = N * C * OUT_H * OUT_W;
    if (idx >= total) return;
    int pw = idx % OUT_W;
    int ph = (idx / OUT_W) % OUT_H;
    int c  = (idx / (OUT_W * OUT_H)) % C;
    int n  = idx / (OUT_W * OUT_H * C);
    const float* r = rois + (size_t)n * 5;
    int   b  = (int)r[0];
    float x1 = r[1] * SCALE, y1 = r[2] * SCALE;
    float roi_w = fmaxf(r[3] * SCALE - x1, 1.0f);
    float roi_h = fmaxf(r[4] * SCALE - y1, 1.0f);
    float step_y = roi_h * (1.0f / (OUT_H * RATIO));
    float step_x = roi_w * (1.0f / (OUT_W * RATIO));
    const float* fptr = feat + ((size_t)b * C + c) * (size_t)(H * W);
    float acc = 0.0f;
    #pragma unroll
    for (int iy = 0; iy < RATIO; ++iy) {
        float y = y1 + ((float)(ph * RATIO + iy) + 0.5f) * step_y;
        bool vy = (y >= -1.0f) && (y <= (float)H);
        float ycl = fminf(fmaxf(y, 0.0f), (float)(H - 1));
        int y0 = (int)floorf(ycl), y1i = min(y0 + 1, H - 1);
        float ly = ycl - (float)y0, hy = 1.0f - ly;
        #pragma unroll
        for (int ix = 0; ix < RATIO; ++ix) {
            float x = x1 + ((float)(pw * RATIO + ix) + 0.5f) * step_x;
            bool vx = (x >= -1.0f) && (x <= (float)W);
            float xcl = fminf(fmaxf(x, 0.0f), (float)(W - 1));
            int x0 = (int)floorf(xcl), x1i = min(x0 + 1, W - 1);
            float lx = xcl - (float)x0, hx = 1.0f - lx;
            const float* row0 = fptr + (size_t)y0 * W;
            const float* row1 = fptr + (size_t)y1i * W;
            float v = hy * hx * row0[x0] + hy * lx * row0[x1i]
                    + ly * hx * row1[x0] + ly * lx * row1[x1i];
            acc += (vy && vx) ? v : 0.0f;
        }
    }
    out[idx] = acc * (1.0f / (RATIO * RATIO));
}

extern "C" void kernel_launch(void* const* d_in, const int* in_sizes, int n_in,
                              void* d_out, int out_size, void* d_ws, size_t ws_size,
                              hipStream_t stream) {
    const float* feat = (const float*)d_in[0];
    const float* rois = (const float*)d_in[1];
    float* out = (float*)d_out;

    const int N = in_sizes[1] / 5;
    const int B = in_sizes[0] / (CCH * FHW);

    size_t need = (size_t)B * FHW * CCH * sizeof(__half);
    if (ws_size >= need) {
        __half* featT = (__half*)d_ws;
        transpose_cp<<<B * 4 * 625, 256, 0, stream>>>(feat, featT);
        roi_gather_v12<<<4 * N, 256, 0, stream>>>(featT, rois, out, N);
    } else {
        int total = N * CCH * OUT_H * OUT_W;
        roi_align_kernel<<<(total + 255) / 256, 256, 0, stream>>>(
            feat, rois, out, N, CCH, FH, FW);
    }
}

// Round 15
// 60.208 us; speedup vs baseline: 1.3048x; 1.3048x over previous
//
#include <hip/hip_runtime.h>
#include <hip/hip_fp16.h>

#define OUT_H 7
#define OUT_W 7
#define NPOS  49
#define RATIO 2
#define SCALE 0.25f
#define CCH 256
#define FH 200
#define FW 200
#define FHW (FH * FW)          // 40000
#define LROW 65                // ODD row stride (floats): bank stride 1 -> conflict-free

struct __align__(16) H8 { __half2 h[4]; };   // 8 fp16 channels

__device__ __forceinline__ void acc8(float (&a)[8], const H8& v, float w) {
    #pragma unroll
    for (int k = 0; k < 4; ++k) {
        a[2*k]   = fmaf(__low2float(v.h[k]),  w, a[2*k]);
        a[2*k+1] = fmaf(__high2float(v.h[k]), w, a[2*k+1]);
    }
}

// ---------------- Transpose: (B, 256, 40000) fp32 -> (B, 40000, 256) fp16 ---
// HBM-bound at ~15 us (123 MB moved). Scalar coalesced loads, ushort LDS
// tile (2-way max conflicts), uint stores.
__global__ __launch_bounds__(256) void transpose_cp(
    const float* __restrict__ in, __half* __restrict__ outT)
{
    int bid = blockIdx.x;               // grid = B * 4 * 625
    int pt   = bid % 625;               // pixel tile (64 pixels)
    int rest = bid / 625;
    int ct   = rest & 3;                // channel tile (64 ch)
    int b    = rest >> 2;

    __shared__ unsigned short tile[64][66];   // [pix][c]
    int tid = threadIdx.x;
    int pix0 = pt * 64, c0 = ct * 64;
    int xl = tid & 63;

    const float* src = in + ((size_t)b * CCH + c0) * FHW + pix0;
    #pragma unroll
    for (int k = 0; k < 16; ++k) {
        int cl = (tid >> 6) + 4 * k;    // 0..63
        tile[xl][cl] = __half_as_ushort(__float2half(src[(size_t)cl * FHW + xl]));
    }
    __syncthreads();

    __half* dst = outT + ((size_t)b * FHW + pix0) * CCH + c0;
    #pragma unroll
    for (int j = 0; j < 8; ++j) {
        int idx = tid + 256 * j;        // 0..2047
        int pl = idx >> 5;              // 0..63
        int cp = idx & 31;              // half2 index: c = 2*cp
        *(unsigned int*)((char*)dst + (size_t)pl * (CCH * 2) + 4 * cp) =
            *(const unsigned int*)&tile[pl][2 * cp];
    }
}

// ---------------- ROI Align gather (round-11 best: ~45 us) ------------------
// grid = 4N: block (n = bid>>2, cq = bid&3) owns 64 channels of ROI n.
// Per position: compute all corner addrs/weights, issue ALL 16 H8 loads,
// sched_barrier(0), then 128 cvt-folded FMAs. This sits at the L1 miss-
// processing floor (~6.3M 64B line-requests; ~4 cy/miss/CU): five
// structurally different variants (coherent bursts, async global_load_lds
// pipelines, table-driven) all measured equal or worse.
__global__ __launch_bounds__(256, 4) void roi_gather_v9(
    const __half* __restrict__ featT,  // (B, 40000, 256) fp16
    const float* __restrict__ rois,    // (N, 5)
    float* __restrict__ out,           // (N, 256, 7, 7)
    int N)
{
    int bid = blockIdx.x;
    int n  = bid >> 2;
    int cq = bid & 3;
    int tid = threadIdx.x;
    int wave = tid >> 6, lane = tid & 63;
    int g = lane >> 3;                  // position group 0..7
    int l = lane & 7;                   // channel group (8 ch)

    __shared__ float lds[NPOS * LROW];

    const float* r = rois + (size_t)n * 5;
    int   b  = (int)r[0];
    float x1 = r[1] * SCALE, y1 = r[2] * SCALE;
    float roi_w = fmaxf(r[3] * SCALE - x1, 1.0f);
    float roi_h = fmaxf(r[4] * SCALE - y1, 1.0f);
    float step_x = roi_w * (1.0f / (OUT_W * RATIO));
    float step_y = roi_h * (1.0f / (OUT_H * RATIO));

    const char* base = (const char*)featT + (size_t)b * ((size_t)FHW * CCH * 2);
    const uint32_t laneoff = (uint32_t)(cq * 64 + l * 8) * 2;

    #pragma unroll 1
    for (int rnd = 0; rnd < 2; ++rnd) {
        int p = rnd * 32 + wave * 8 + g;    // 0..63
        if (p < NPOS) {
            int ph = p / OUT_W;
            int pw = p - ph * OUT_W;

            uint32_t o00[4], dxx[4], rst[4];
            float w[4][4];
            #pragma unroll
            for (int iy = 0; iy < RATIO; ++iy) {
                float yy = y1 + ((float)(ph * RATIO + iy) + 0.5f) * step_y;
                bool  vy = (yy >= -1.0f) && (yy <= (float)FH);
                float yc = fminf(fmaxf(yy, 0.0f), (float)(FH - 1));
                int   yi0 = (int)yc;
                float ly = yc - (float)yi0, hy = 1.0f - ly;
                uint32_t row0  = (uint32_t)yi0 * (FW * CCH * 2);
                uint32_t rstep = (yi0 < FH - 1) ? (FW * CCH * 2) : 0u;
                #pragma unroll
                for (int ix = 0; ix < RATIO; ++ix) {
                    int s = iy * RATIO + ix;
                    float xx = x1 + ((float)(pw * RATIO + ix) + 0.5f) * step_x;
                    bool  vx = (xx >= -1.0f) && (xx <= (float)FW);
                    float xc = fminf(fmaxf(xx, 0.0f), (float)(FW - 1));
                    int   xi0 = (int)xc;
                    float lx = xc - (float)xi0, hx = 1.0f - lx;
                    float vm  = (vy && vx) ? 0.25f : 0.0f;
                    float hyv = hy * vm, lyv = ly * vm;
                    o00[s] = row0 + (uint32_t)xi0 * (CCH * 2) + laneoff;
                    dxx[s] = (xi0 < FW - 1) ? (CCH * 2) : 0u;
                    rst[s] = rstep;
                    w[s][0] = hyv * hx; w[s][1] = hyv * lx;
                    w[s][2] = lyv * hx; w[s][3] = lyv * lx;
                }
            }

            H8 v[16];
            #pragma unroll
            for (int s = 0; s < 4; ++s) {
                v[4*s+0] = *(const H8*)(base + o00[s]);
                v[4*s+1] = *(const H8*)(base + o00[s] + dxx[s]);
                v[4*s+2] = *(const H8*)(base + o00[s] + rst[s]);
                v[4*s+3] = *(const H8*)(base + o00[s] + rst[s] + dxx[s]);
            }
            // Hard scheduling fence: all 16 loads issue before any FMA.
            __builtin_amdgcn_sched_barrier(0);

            float acc[8];
            #pragma unroll
            for (int k = 0; k < 8; ++k) acc[k] = 0.0f;
            #pragma unroll
            for (int s = 0; s < 4; ++s) {
                #pragma unroll
                for (int c4 = 0; c4 < 4; ++c4)
                    acc8(acc, v[4*s+c4], w[s][c4]);
            }

            // Scalar LDS writes: bank = (p + 8l + k) & 31 -> 2/bank = free.
            float* lp = &lds[p * LROW + l * 8];
            #pragma unroll
            for (int k = 0; k < 8; ++k) lp[k] = acc[k];
        }
    }
    __syncthreads();

    // Contiguous 64*49-float region of (N,C,7,7); write-once -> nontemporal.
    // Read bank stride 1 (LROW odd) -> conflict-free.
    float* oblk = out + ((size_t)n * CCH + cq * 64) * NPOS;
    #pragma unroll 1
    for (int o = tid; o < 64 * NPOS; o += 256) {
        int c = o / NPOS;          // magic-mul
        int p = o - c * NPOS;
        __builtin_nontemporal_store(lds[p * LROW + c], &oblk[o]);
    }
}

// ---------------- Fallback: direct NCHW (round-1 kernel) --------------------
__global__ __launch_bounds__(256) void roi_align_kernel(
    const float* __restrict__ feat, const float* __restrict__ rois,
    float* __restrict__ out, int N, int C, int H, int W)
{
    int idx = blockIdx.x * blockDim.x + threadIdx.x;
    int total = N * C * OUT_H * OUT_W;
    if (idx >= total) return;
    int pw = idx % OUT_W;
    int ph = (idx / OUT_W) % OUT_H;
    int c  = (idx / (OUT_W * OUT_H)) % C;
    int n  = idx / (OUT_W * OUT_H * C);
    const float* r = rois + (size_t)n * 5;
    int   b  = (int)r[0];
    float x1 = r[1] * SCALE, y1 = r[2] * SCALE;
    float roi_w = fmaxf(r[3] * SCALE - x1, 1.0f);
    float roi_h = fmaxf(r[4] * SCALE - y1, 1.0f);
    float step_y = roi_h * (1.0f / (OUT_H * RATIO));
    float step_x = roi_w * (1.0f / (OUT_W * RATIO));
    const float* fptr = feat + ((size_t)b * C + c) * (size_t)(H * W);
    float acc = 0.0f;
    #pragma unroll
    for (int iy = 0; iy < RATIO; ++iy) {
        float y = y1 + ((float)(ph * RATIO + iy) + 0.5f) * step_y;
        bool vy = (y >= -1.0f) && (y <= (float)H);
        float ycl = fminf(fmaxf(y, 0.0f), (float)(H - 1));
        int y0 = (int)floorf(ycl), y1i = min(y0 + 1, H - 1);
        float ly = ycl - (float)y0, hy = 1.0f - ly;
        #pragma unroll
        for (int ix = 0; ix < RATIO; ++ix) {
            float x = x1 + ((float)(pw * RATIO + ix) + 0.5f) * step_x;
            bool vx = (x >= -1.0f) && (x <= (float)W);
            float xcl = fminf(fmaxf(x, 0.0f), (float)(W - 1));
            int x0 = (int)floorf(xcl), x1i = min(x0 + 1, W - 1);
            float lx = xcl - (float)x0, hx = 1.0f - lx;
            const float* row0 = fptr + (size_t)y0 * W;
            const float* row1 = fptr + (size_t)y1i * W;
            float v = hy * hx * row0[x0] + hy * lx * row0[x1i]
                    + ly * hx * row1[x0] + ly * lx * row1[x1i];
            acc += (vy && vx) ? v : 0.0f;
        }
    }
    out[idx] = acc * (1.0f / (RATIO * RATIO));
}

extern "C" void kernel_launch(void* const* d_in, const int* in_sizes, int n_in,
                              void* d_out, int out_size, void* d_ws, size_t ws_size,
                              hipStream_t stream) {
    const float* feat = (const float*)d_in[0];
    const float* rois = (const float*)d_in[1];
    float* out = (float*)d_out;

    const int N = in_sizes[1] / 5;
    const int B = in_sizes[0] / (CCH * FHW);

    size_t need = (size_t)B * FHW * CCH * sizeof(__half);
    if (ws_size >= need) {
        __half* featT = (__half*)d_ws;
        transpose_cp<<<B * 4 * 625, 256, 0, stream>>>(feat, featT);
        roi_gather_v9<<<4 * N, 256, 0, stream>>>(featT, rois, out, N);
    } else {
        int total = N * CCH * OUT_H * OUT_W;
        roi_align_kernel<<<(total + 255) / 256, 256, 0, stream>>>(
            feat, rois, out, N, CCH, FH, FW);
    }
}